// Round 1
// baseline (935.725 us; speedup 1.0000x reference)
//
#include <hip/hip_runtime.h>
#include <cstdint>
#include <cstddef>

#define NPIX 4096   // H*W = 64*64
#define CIN  256
#define CQK  32
#define BSZ  4

// ---------------- Kernel 1: 1x1-conv projection ----------------
// y[b,o,n] = sum_c W[o,c] * x[b,c,n] + bias[o]
// grid (NPIX/1024, Cout/8, B), block 256.
// Each thread: 4 consecutive n (float4 x loads), 8 output channels.
// W rows for this block staged in LDS (broadcast reads, unrolled -> ds_read_b128).
__global__ __launch_bounds__(256) void proj_kernel(
    const float* __restrict__ x, const float* __restrict__ W,
    const float* __restrict__ bias, float* __restrict__ y, int Cout)
{
    __shared__ float Wl[8][CIN];
    const int t  = threadIdx.x;
    const int n0 = blockIdx.x * 1024;
    const int o0 = blockIdx.y * 8;
    const int b  = blockIdx.z;

    #pragma unroll
    for (int j = 0; j < 8; ++j) {
        int flat = t + 256 * j;           // 2048 elements total
        int row = flat >> 8, col = flat & 255;
        Wl[row][col] = W[(o0 + row) * CIN + col];
    }
    __syncthreads();

    float acc[8][4];
    #pragma unroll
    for (int o = 0; o < 8; ++o)
        #pragma unroll
        for (int i = 0; i < 4; ++i) acc[o][i] = 0.f;

    const float* xb = x + ((size_t)b * CIN) * NPIX + n0 + t * 4;
    #pragma unroll 4
    for (int c = 0; c < CIN; ++c) {
        float4 xv = *(const float4*)(xb + (size_t)c * NPIX);
        #pragma unroll
        for (int o = 0; o < 8; ++o) {
            float w = Wl[o][c];
            acc[o][0] = fmaf(w, xv.x, acc[o][0]);
            acc[o][1] = fmaf(w, xv.y, acc[o][1]);
            acc[o][2] = fmaf(w, xv.z, acc[o][2]);
            acc[o][3] = fmaf(w, xv.w, acc[o][3]);
        }
    }
    #pragma unroll
    for (int o = 0; o < 8; ++o) {
        float bb = bias[o0 + o];
        float4 r = { acc[o][0] + bb, acc[o][1] + bb,
                     acc[o][2] + bb, acc[o][3] + bb };
        *(float4*)(y + ((size_t)(b * Cout + o0 + o)) * NPIX + n0 + t * 4) = r;
    }
}

// ---------------- Kernel 2: energy + softmax (fused) ----------------
// energy[b,n,m] = sum_c q[b,c,n] * k[b,c,m]; softmax over n (per column m);
// write attn directly as at_map[b,m,n] (the transposed map) -> contiguous rows.
// grid (NPIX/8, B), block 512. Block handles 8 columns m; thread holds 8
// consecutive n per column in registers (8x8 = 64 scores/thread).
__global__ __launch_bounds__(512) void energy_softmax_kernel(
    const float* __restrict__ q, const float* __restrict__ k,
    float* __restrict__ at_map)
{
    __shared__ float kk[8][CQK];
    __shared__ float wred[8];
    const int t  = threadIdx.x;
    const int m0 = blockIdx.x * 8;
    const int b  = blockIdx.y;
    const int lane = t & 63, wid = t >> 6;   // 8 waves

    if (t < 256) {
        int c = t >> 3, mi = t & 7;
        kk[mi][c] = k[((size_t)(b * CQK + c)) * NPIX + m0 + mi];
    }
    __syncthreads();

    float s[8][8];
    #pragma unroll
    for (int mi = 0; mi < 8; ++mi)
        #pragma unroll
        for (int i = 0; i < 8; ++i) s[mi][i] = 0.f;

    const float* qb = q + ((size_t)b * CQK) * NPIX + t * 8;
    #pragma unroll 2
    for (int c = 0; c < CQK; ++c) {
        float4 q0 = *(const float4*)(qb + (size_t)c * NPIX);
        float4 q1 = *(const float4*)(qb + (size_t)c * NPIX + 4);
        #pragma unroll
        for (int mi = 0; mi < 8; ++mi) {
            float w = kk[mi][c];
            s[mi][0] = fmaf(w, q0.x, s[mi][0]);
            s[mi][1] = fmaf(w, q0.y, s[mi][1]);
            s[mi][2] = fmaf(w, q0.z, s[mi][2]);
            s[mi][3] = fmaf(w, q0.w, s[mi][3]);
            s[mi][4] = fmaf(w, q1.x, s[mi][4]);
            s[mi][5] = fmaf(w, q1.y, s[mi][5]);
            s[mi][6] = fmaf(w, q1.z, s[mi][6]);
            s[mi][7] = fmaf(w, q1.w, s[mi][7]);
        }
    }

    #pragma unroll
    for (int mi = 0; mi < 8; ++mi) {
        // block max over 4096 scores of column m0+mi
        float mx = s[mi][0];
        #pragma unroll
        for (int i = 1; i < 8; ++i) mx = fmaxf(mx, s[mi][i]);
        #pragma unroll
        for (int off = 1; off < 64; off <<= 1)
            mx = fmaxf(mx, __shfl_xor(mx, off, 64));
        if (lane == 0) wred[wid] = mx;
        __syncthreads();
        float bmx = wred[0];
        #pragma unroll
        for (int w = 1; w < 8; ++w) bmx = fmaxf(bmx, wred[w]);
        __syncthreads();

        // exp + block sum
        float sum = 0.f;
        #pragma unroll
        for (int i = 0; i < 8; ++i) {
            s[mi][i] = __expf(s[mi][i] - bmx);
            sum += s[mi][i];
        }
        #pragma unroll
        for (int off = 1; off < 64; off <<= 1)
            sum += __shfl_xor(sum, off, 64);
        if (lane == 0) wred[wid] = sum;
        __syncthreads();
        float bsum = 0.f;
        #pragma unroll
        for (int w = 0; w < 8; ++w) bsum += wred[w];
        __syncthreads();

        float inv = 1.f / bsum;
        float* dst = at_map + ((size_t)(b * NPIX) + m0 + mi) * NPIX + t * 8;
        float4 r0 = { s[mi][0]*inv, s[mi][1]*inv, s[mi][2]*inv, s[mi][3]*inv };
        float4 r1 = { s[mi][4]*inv, s[mi][5]*inv, s[mi][6]*inv, s[mi][7]*inv };
        *(float4*)(dst)     = r0;
        *(float4*)(dst + 4) = r1;
    }
}

// ---------------- Kernel 3: sa = v @ attn, out = x + gamma*sa ----------------
// sa[b,c,m] = sum_n v[b,c,n] * at_map[b,m,n]   (NT gemm, both row-major in n)
// grid (NPIX/64, CIN/64, B), block 256. 64x64 tile, BK=32, K-major LDS tiles
// (pad 68) so compute does conflict-free ds_read_b128. 4x4 accum per thread.
__global__ __launch_bounds__(256) void sa_gemm_kernel(
    const float* __restrict__ v, const float* __restrict__ at_map,
    const float* __restrict__ x, const float* __restrict__ gptr,
    float* __restrict__ out)
{
    __shared__ float Vt[32][68];
    __shared__ float At[32][68];
    const int t  = threadIdx.x;
    const int m0 = blockIdx.x * 64;
    const int c0 = blockIdx.y * 64;
    const int b  = blockIdx.z;
    const int r  = t >> 2, qd = t & 3;   // load mapping: row 0..63, quad 0..3
    const int tc = t & 15, tm = t >> 4;  // compute mapping: 16x16 threads, 4x4 each

    const float* vb = v      + ((size_t)(b * CIN  + c0 + r)) * NPIX + qd * 4;
    const float* ab = at_map + ((size_t)(b * NPIX + m0 + r)) * NPIX + qd * 4;

    float acc[4][4];
    #pragma unroll
    for (int i = 0; i < 4; ++i)
        #pragma unroll
        for (int j = 0; j < 4; ++j) acc[i][j] = 0.f;

    for (int n0 = 0; n0 < NPIX; n0 += 32) {
        float4 v0 = *(const float4*)(vb + n0);
        float4 v1 = *(const float4*)(vb + n0 + 16);
        float4 a0 = *(const float4*)(ab + n0);
        float4 a1 = *(const float4*)(ab + n0 + 16);
        // transposed (K-major) store; 2-way bank aliasing only (free on CDNA4)
        Vt[qd*4+0][r] = v0.x; Vt[qd*4+1][r] = v0.y;
        Vt[qd*4+2][r] = v0.z; Vt[qd*4+3][r] = v0.w;
        Vt[16+qd*4+0][r] = v1.x; Vt[16+qd*4+1][r] = v1.y;
        Vt[16+qd*4+2][r] = v1.z; Vt[16+qd*4+3][r] = v1.w;
        At[qd*4+0][r] = a0.x; At[qd*4+1][r] = a0.y;
        At[qd*4+2][r] = a0.z; At[qd*4+3][r] = a0.w;
        At[16+qd*4+0][r] = a1.x; At[16+qd*4+1][r] = a1.y;
        At[16+qd*4+2][r] = a1.z; At[16+qd*4+3][r] = a1.w;
        __syncthreads();
        #pragma unroll
        for (int kk = 0; kk < 32; ++kk) {
            float4 a  = *(const float4*)&Vt[kk][tc * 4];
            float4 bb = *(const float4*)&At[kk][tm * 4];
            acc[0][0] = fmaf(a.x, bb.x, acc[0][0]);
            acc[0][1] = fmaf(a.x, bb.y, acc[0][1]);
            acc[0][2] = fmaf(a.x, bb.z, acc[0][2]);
            acc[0][3] = fmaf(a.x, bb.w, acc[0][3]);
            acc[1][0] = fmaf(a.y, bb.x, acc[1][0]);
            acc[1][1] = fmaf(a.y, bb.y, acc[1][1]);
            acc[1][2] = fmaf(a.y, bb.z, acc[1][2]);
            acc[1][3] = fmaf(a.y, bb.w, acc[1][3]);
            acc[2][0] = fmaf(a.z, bb.x, acc[2][0]);
            acc[2][1] = fmaf(a.z, bb.y, acc[2][1]);
            acc[2][2] = fmaf(a.z, bb.z, acc[2][2]);
            acc[2][3] = fmaf(a.z, bb.w, acc[2][3]);
            acc[3][0] = fmaf(a.w, bb.x, acc[3][0]);
            acc[3][1] = fmaf(a.w, bb.y, acc[3][1]);
            acc[3][2] = fmaf(a.w, bb.z, acc[3][2]);
            acc[3][3] = fmaf(a.w, bb.w, acc[3][3]);
        }
        __syncthreads();
    }

    const float g = *gptr;
    #pragma unroll
    for (int i = 0; i < 4; ++i) {
        size_t row = ((size_t)(b * CIN + c0 + tc * 4 + i)) * NPIX + m0 + tm * 4;
        float4 xv = *(const float4*)(x + row);
        float4 o  = { xv.x + g * acc[i][0], xv.y + g * acc[i][1],
                      xv.z + g * acc[i][2], xv.w + g * acc[i][3] };
        *(float4*)(out + row) = o;
    }
}

extern "C" void kernel_launch(void* const* d_in, const int* in_sizes, int n_in,
                              void* d_out, int out_size, void* d_ws, size_t ws_size,
                              hipStream_t stream) {
    const float* x     = (const float*)d_in[0];   // [B, C, N]  (B,C,H,W flat)
    const float* wq    = (const float*)d_in[1];   // [32, 256]
    const float* bq    = (const float*)d_in[2];   // [32]
    const float* wk    = (const float*)d_in[3];   // [32, 256]
    const float* bk    = (const float*)d_in[4];   // [32]
    const float* wv    = (const float*)d_in[5];   // [256, 256]
    const float* bv    = (const float*)d_in[6];   // [256]
    const float* gamma = (const float*)d_in[7];   // [1]

    float* out    = (float*)d_out;                           // [B,C,H,W]
    float* at_map = out + (size_t)BSZ * CIN * NPIX;          // [B,N,N]

    // workspace: q [B,32,N], k [B,32,N], v [B,256,N]  -> 20 MB total
    float* q = (float*)d_ws;
    float* k = q + (size_t)BSZ * CQK * NPIX;
    float* v = k + (size_t)BSZ * CQK * NPIX;

    proj_kernel<<<dim3(NPIX / 1024, CQK / 8, BSZ), 256, 0, stream>>>(x, wq, bq, q, CQK);
    proj_kernel<<<dim3(NPIX / 1024, CQK / 8, BSZ), 256, 0, stream>>>(x, wk, bk, k, CQK);
    proj_kernel<<<dim3(NPIX / 1024, CIN / 8, BSZ), 256, 0, stream>>>(x, wv, bv, v, CIN);

    energy_softmax_kernel<<<dim3(NPIX / 8, BSZ), 512, 0, stream>>>(q, k, at_map);

    sa_gemm_kernel<<<dim3(NPIX / 64, CIN / 64, BSZ), 256, 0, stream>>>(
        v, at_map, x, gamma, out);
}

// Round 2
// 626.410 us; speedup vs baseline: 1.4938x; 1.4938x over previous
//
#include <hip/hip_runtime.h>
#include <hip/hip_bf16.h>
#include <cstdint>
#include <cstddef>

#define NPIX 4096   // H*W = 64*64
#define CIN  256
#define CQK  32
#define BSZ  4

typedef __attribute__((ext_vector_type(8))) short          bf16x8;
typedef __attribute__((ext_vector_type(4))) float          f32x4;
typedef __attribute__((ext_vector_type(8))) unsigned short u16x8;

static __device__ inline unsigned short f2bf(float f) {
    __hip_bfloat16 h = __float2bfloat16(f);   // RNE
    unsigned short u;
    __builtin_memcpy(&u, &h, 2);
    return u;
}

static __device__ inline void gl2lds16(const void* g, void* l) {
    // 16B-per-lane direct global->LDS; LDS dest is wave-uniform base + lane*16
    __builtin_amdgcn_global_load_lds(
        (const __attribute__((address_space(1))) unsigned int*)g,
        (__attribute__((address_space(3))) unsigned int*)l,
        16, 0, 0);
}

// ---------------- Kernel 1a: 1x1-conv projection, fp32 out (q, k) ----------
__global__ __launch_bounds__(256) void proj_kernel(
    const float* __restrict__ x, const float* __restrict__ W,
    const float* __restrict__ bias, float* __restrict__ y, int Cout)
{
    __shared__ float Wl[8][CIN];
    const int t  = threadIdx.x;
    const int n0 = blockIdx.x * 1024;
    const int o0 = blockIdx.y * 8;
    const int b  = blockIdx.z;

    #pragma unroll
    for (int j = 0; j < 8; ++j) {
        int flat = t + 256 * j;
        int row = flat >> 8, col = flat & 255;
        Wl[row][col] = W[(o0 + row) * CIN + col];
    }
    __syncthreads();

    float acc[8][4];
    #pragma unroll
    for (int o = 0; o < 8; ++o)
        #pragma unroll
        for (int i = 0; i < 4; ++i) acc[o][i] = 0.f;

    const float* xb = x + ((size_t)b * CIN) * NPIX + n0 + t * 4;
    #pragma unroll 4
    for (int c = 0; c < CIN; ++c) {
        float4 xv = *(const float4*)(xb + (size_t)c * NPIX);
        #pragma unroll
        for (int o = 0; o < 8; ++o) {
            float w = Wl[o][c];
            acc[o][0] = fmaf(w, xv.x, acc[o][0]);
            acc[o][1] = fmaf(w, xv.y, acc[o][1]);
            acc[o][2] = fmaf(w, xv.z, acc[o][2]);
            acc[o][3] = fmaf(w, xv.w, acc[o][3]);
        }
    }
    #pragma unroll
    for (int o = 0; o < 8; ++o) {
        float bb = bias[o0 + o];
        float4 r = { acc[o][0] + bb, acc[o][1] + bb,
                     acc[o][2] + bb, acc[o][3] + bb };
        *(float4*)(y + ((size_t)(b * Cout + o0 + o)) * NPIX + n0 + t * 4) = r;
    }
}

// ---------------- Kernel 1b: 1x1-conv projection, bf16 out (v) -------------
__global__ __launch_bounds__(256) void proj_bf16_kernel(
    const float* __restrict__ x, const float* __restrict__ W,
    const float* __restrict__ bias, unsigned short* __restrict__ y, int Cout)
{
    __shared__ float Wl[8][CIN];
    const int t  = threadIdx.x;
    const int n0 = blockIdx.x * 1024;
    const int o0 = blockIdx.y * 8;
    const int b  = blockIdx.z;

    #pragma unroll
    for (int j = 0; j < 8; ++j) {
        int flat = t + 256 * j;
        int row = flat >> 8, col = flat & 255;
        Wl[row][col] = W[(o0 + row) * CIN + col];
    }
    __syncthreads();

    float acc[8][4];
    #pragma unroll
    for (int o = 0; o < 8; ++o)
        #pragma unroll
        for (int i = 0; i < 4; ++i) acc[o][i] = 0.f;

    const float* xb = x + ((size_t)b * CIN) * NPIX + n0 + t * 4;
    #pragma unroll 4
    for (int c = 0; c < CIN; ++c) {
        float4 xv = *(const float4*)(xb + (size_t)c * NPIX);
        #pragma unroll
        for (int o = 0; o < 8; ++o) {
            float w = Wl[o][c];
            acc[o][0] = fmaf(w, xv.x, acc[o][0]);
            acc[o][1] = fmaf(w, xv.y, acc[o][1]);
            acc[o][2] = fmaf(w, xv.z, acc[o][2]);
            acc[o][3] = fmaf(w, xv.w, acc[o][3]);
        }
    }
    #pragma unroll
    for (int o = 0; o < 8; ++o) {
        float bb = bias[o0 + o];
        ushort4 r;
        r.x = f2bf(acc[o][0] + bb);
        r.y = f2bf(acc[o][1] + bb);
        r.z = f2bf(acc[o][2] + bb);
        r.w = f2bf(acc[o][3] + bb);
        *(ushort4*)(y + ((size_t)(b * Cout + o0 + o)) * NPIX + n0 + t * 4) = r;
    }
}

// ---------------- Kernel 2: energy + softmax (fused) -----------------------
// writes fp32 at_map[b,m,n] AND (optionally) a bf16 copy for the MFMA GEMM.
__global__ __launch_bounds__(512) void energy_softmax_kernel(
    const float* __restrict__ q, const float* __restrict__ k,
    float* __restrict__ at_map, unsigned short* __restrict__ attn_bf)
{
    __shared__ float kk[8][CQK];
    __shared__ float wred[8];
    const int t  = threadIdx.x;
    const int m0 = blockIdx.x * 8;
    const int b  = blockIdx.y;
    const int lane = t & 63, wid = t >> 6;

    if (t < 256) {
        int c = t >> 3, mi = t & 7;
        kk[mi][c] = k[((size_t)(b * CQK + c)) * NPIX + m0 + mi];
    }
    __syncthreads();

    float s[8][8];
    #pragma unroll
    for (int mi = 0; mi < 8; ++mi)
        #pragma unroll
        for (int i = 0; i < 8; ++i) s[mi][i] = 0.f;

    const float* qb = q + ((size_t)b * CQK) * NPIX + t * 8;
    #pragma unroll 2
    for (int c = 0; c < CQK; ++c) {
        float4 q0 = *(const float4*)(qb + (size_t)c * NPIX);
        float4 q1 = *(const float4*)(qb + (size_t)c * NPIX + 4);
        #pragma unroll
        for (int mi = 0; mi < 8; ++mi) {
            float w = kk[mi][c];
            s[mi][0] = fmaf(w, q0.x, s[mi][0]);
            s[mi][1] = fmaf(w, q0.y, s[mi][1]);
            s[mi][2] = fmaf(w, q0.z, s[mi][2]);
            s[mi][3] = fmaf(w, q0.w, s[mi][3]);
            s[mi][4] = fmaf(w, q1.x, s[mi][4]);
            s[mi][5] = fmaf(w, q1.y, s[mi][5]);
            s[mi][6] = fmaf(w, q1.z, s[mi][6]);
            s[mi][7] = fmaf(w, q1.w, s[mi][7]);
        }
    }

    #pragma unroll
    for (int mi = 0; mi < 8; ++mi) {
        float mx = s[mi][0];
        #pragma unroll
        for (int i = 1; i < 8; ++i) mx = fmaxf(mx, s[mi][i]);
        #pragma unroll
        for (int off = 1; off < 64; off <<= 1)
            mx = fmaxf(mx, __shfl_xor(mx, off, 64));
        if (lane == 0) wred[wid] = mx;
        __syncthreads();
        float bmx = wred[0];
        #pragma unroll
        for (int w = 1; w < 8; ++w) bmx = fmaxf(bmx, wred[w]);
        __syncthreads();

        float sum = 0.f;
        #pragma unroll
        for (int i = 0; i < 8; ++i) {
            s[mi][i] = __expf(s[mi][i] - bmx);
            sum += s[mi][i];
        }
        #pragma unroll
        for (int off = 1; off < 64; off <<= 1)
            sum += __shfl_xor(sum, off, 64);
        if (lane == 0) wred[wid] = sum;
        __syncthreads();
        float bsum = 0.f;
        #pragma unroll
        for (int w = 0; w < 8; ++w) bsum += wred[w];
        __syncthreads();

        float inv = 1.f / bsum;
        size_t rowoff = ((size_t)(b * NPIX) + m0 + mi) * NPIX + t * 8;
        float a0 = s[mi][0]*inv, a1 = s[mi][1]*inv, a2 = s[mi][2]*inv, a3 = s[mi][3]*inv;
        float a4 = s[mi][4]*inv, a5 = s[mi][5]*inv, a6 = s[mi][6]*inv, a7 = s[mi][7]*inv;
        float4 r0 = { a0, a1, a2, a3 };
        float4 r1 = { a4, a5, a6, a7 };
        *(float4*)(at_map + rowoff)     = r0;
        *(float4*)(at_map + rowoff + 4) = r1;
        if (attn_bf) {
            u16x8 rb;
            rb[0] = f2bf(a0); rb[1] = f2bf(a1); rb[2] = f2bf(a2); rb[3] = f2bf(a3);
            rb[4] = f2bf(a4); rb[5] = f2bf(a5); rb[6] = f2bf(a6); rb[7] = f2bf(a7);
            *(u16x8*)(attn_bf + rowoff) = rb;
        }
    }
}

// ---------------- Kernel 3 (fast): sa = V*attn^T via bf16 MFMA -------------
// O[c,m] = sum_n V[c,n]*attn[m,n]; both operands K-major (n contiguous).
// 128x128 block tile, BK=64, global_load_lds width-16, XOR granule swizzle
// (granule ^ row&7) so ds_read_b128 phases spread 2 lanes/bank (free).
// 4 waves, each 64x64 = 4x4 frags of mfma_f32_16x16x32_bf16.
__global__ __launch_bounds__(256) void sa_gemm_mfma(
    const unsigned short* __restrict__ v,     // [B,CIN,N] bf16
    const unsigned short* __restrict__ attn,  // [B,N,N]  bf16
    const float* __restrict__ x, const float* __restrict__ gptr,
    float* __restrict__ out)
{
    __shared__ __align__(16) unsigned short As[128 * 64];  // 16 KB
    __shared__ __align__(16) unsigned short Bs[128 * 64];  // 16 KB

    const int t = threadIdx.x, lane = t & 63, w = t >> 6;
    const int m_base = blockIdx.x * 128;
    const int c_base = blockIdx.y * 128;
    const int b      = blockIdx.z;
    const int wc = (w >> 1) * 64, wm = (w & 1) * 64;

    // ---- staging lane mapping: 8 rows x 8 granules(16B) per instruction ----
    const int lrow = lane >> 3;            // row within 8-row group
    const int glog = (lane & 7) ^ lrow;    // swizzled logical granule
    const unsigned short* aSrc[4];
    const unsigned short* bSrc[4];
    #pragma unroll
    for (int qi = 0; qi < 4; ++qi) {
        int r = w * 32 + qi * 8 + lrow;    // tile-local row this lane fetches
        aSrc[qi] = v    + ((size_t)(b * CIN + c_base + r)) * NPIX + glog * 8;
        bSrc[qi] = attn + ((size_t)b * NPIX + m_base + r) * NPIX + glog * 8;
    }

    // ---- compute lane mapping ----
    const int l15 = lane & 15, q4 = lane >> 4;
    const int x0 = (q4 ^ (lane & 7)) * 8;          // kstep0 swizzled elem off
    const int x1 = ((q4 ^ 4) ^ (lane & 7)) * 8;    // kstep1
    const int baseA = (wc + l15) * 64;
    const int baseB = (wm + l15) * 64;

    f32x4 acc[4][4];
    #pragma unroll
    for (int i = 0; i < 4; ++i)
        #pragma unroll
        for (int j = 0; j < 4; ++j) acc[i][j] = (f32x4)(0.0f);

    for (int k0 = 0; k0 < NPIX; k0 += 64) {
        #pragma unroll
        for (int qi = 0; qi < 4; ++qi) {
            gl2lds16(aSrc[qi] + k0, &As[(w * 32 + qi * 8) * 64]);
            gl2lds16(bSrc[qi] + k0, &Bs[(w * 32 + qi * 8) * 64]);
        }
        __syncthreads();
        #pragma unroll
        for (int ks = 0; ks < 2; ++ks) {
            const int xo = ks ? x1 : x0;
            bf16x8 af[4], bfr[4];
            #pragma unroll
            for (int i = 0; i < 4; ++i)
                af[i] = *(const bf16x8*)&As[baseA + i * 1024 + xo];
            #pragma unroll
            for (int j = 0; j < 4; ++j)
                bfr[j] = *(const bf16x8*)&Bs[baseB + j * 1024 + xo];
            #pragma unroll
            for (int i = 0; i < 4; ++i)
                #pragma unroll
                for (int j = 0; j < 4; ++j)
                    acc[i][j] = __builtin_amdgcn_mfma_f32_16x16x32_bf16(
                        af[i], bfr[j], acc[i][j], 0, 0, 0);
        }
        __syncthreads();
    }

    // ---- epilogue: out = x + gamma*sa.  D: row=(lane>>4)*4+r, col=lane&15 --
    const float g = gptr[0];
    #pragma unroll
    for (int i = 0; i < 4; ++i) {
        int c = c_base + wc + i * 16 + q4 * 4;
        #pragma unroll
        for (int j = 0; j < 4; ++j) {
            int m = m_base + wm + j * 16 + l15;
            #pragma unroll
            for (int r = 0; r < 4; ++r) {
                size_t idx = ((size_t)(b * CIN + c + r)) * NPIX + m;
                out[idx] = x[idx] + g * acc[i][j][r];
            }
        }
    }
}

// ---------------- Kernel 3 (fallback): fp32 VALU GEMM ----------------------
__global__ __launch_bounds__(256) void sa_gemm_kernel(
    const float* __restrict__ v, const float* __restrict__ at_map,
    const float* __restrict__ x, const float* __restrict__ gptr,
    float* __restrict__ out)
{
    __shared__ float Vt[32][68];
    __shared__ float At[32][68];
    const int t  = threadIdx.x;
    const int m0 = blockIdx.x * 64;
    const int c0 = blockIdx.y * 64;
    const int b  = blockIdx.z;
    const int r  = t >> 2, qd = t & 3;
    const int tc = t & 15, tm = t >> 4;

    const float* vb = v      + ((size_t)(b * CIN  + c0 + r)) * NPIX + qd * 4;
    const float* ab = at_map + ((size_t)(b * NPIX + m0 + r)) * NPIX + qd * 4;

    float acc[4][4];
    #pragma unroll
    for (int i = 0; i < 4; ++i)
        #pragma unroll
        for (int j = 0; j < 4; ++j) acc[i][j] = 0.f;

    for (int n0 = 0; n0 < NPIX; n0 += 32) {
        float4 v0 = *(const float4*)(vb + n0);
        float4 v1 = *(const float4*)(vb + n0 + 16);
        float4 a0 = *(const float4*)(ab + n0);
        float4 a1 = *(const float4*)(ab + n0 + 16);
        Vt[qd*4+0][r] = v0.x; Vt[qd*4+1][r] = v0.y;
        Vt[qd*4+2][r] = v0.z; Vt[qd*4+3][r] = v0.w;
        Vt[16+qd*4+0][r] = v1.x; Vt[16+qd*4+1][r] = v1.y;
        Vt[16+qd*4+2][r] = v1.z; Vt[16+qd*4+3][r] = v1.w;
        At[qd*4+0][r] = a0.x; At[qd*4+1][r] = a0.y;
        At[qd*4+2][r] = a0.z; At[qd*4+3][r] = a0.w;
        At[16+qd*4+0][r] = a1.x; At[16+qd*4+1][r] = a1.y;
        At[16+qd*4+2][r] = a1.z; At[16+qd*4+3][r] = a1.w;
        __syncthreads();
        #pragma unroll
        for (int kk = 0; kk < 32; ++kk) {
            float4 a  = *(const float4*)&Vt[kk][tc * 4];
            float4 bb = *(const float4*)&At[kk][tm * 4];
            acc[0][0] = fmaf(a.x, bb.x, acc[0][0]);
            acc[0][1] = fmaf(a.x, bb.y, acc[0][1]);
            acc[0][2] = fmaf(a.x, bb.z, acc[0][2]);
            acc[0][3] = fmaf(a.x, bb.w, acc[0][3]);
            acc[1][0] = fmaf(a.y, bb.x, acc[1][0]);
            acc[1][1] = fmaf(a.y, bb.y, acc[1][1]);
            acc[1][2] = fmaf(a.y, bb.z, acc[1][2]);
            acc[1][3] = fmaf(a.y, bb.w, acc[1][3]);
            acc[2][0] = fmaf(a.z, bb.x, acc[2][0]);
            acc[2][1] = fmaf(a.z, bb.y, acc[2][1]);
            acc[2][2] = fmaf(a.z, bb.z, acc[2][2]);
            acc[2][3] = fmaf(a.z, bb.w, acc[2][3]);
            acc[3][0] = fmaf(a.w, bb.x, acc[3][0]);
            acc[3][1] = fmaf(a.w, bb.y, acc[3][1]);
            acc[3][2] = fmaf(a.w, bb.z, acc[3][2]);
            acc[3][3] = fmaf(a.w, bb.w, acc[3][3]);
        }
        __syncthreads();
    }

    const float g = *gptr;
    #pragma unroll
    for (int i = 0; i < 4; ++i) {
        size_t row = ((size_t)(b * CIN + c0 + tc * 4 + i)) * NPIX + m0 + tm * 4;
        float4 xv = *(const float4*)(x + row);
        float4 o  = { xv.x + g * acc[i][0], xv.y + g * acc[i][1],
                      xv.z + g * acc[i][2], xv.w + g * acc[i][3] };
        *(float4*)(out + row) = o;
    }
}

extern "C" void kernel_launch(void* const* d_in, const int* in_sizes, int n_in,
                              void* d_out, int out_size, void* d_ws, size_t ws_size,
                              hipStream_t stream) {
    const float* x     = (const float*)d_in[0];
    const float* wq    = (const float*)d_in[1];
    const float* bq    = (const float*)d_in[2];
    const float* wk    = (const float*)d_in[3];
    const float* bk    = (const float*)d_in[4];
    const float* wv    = (const float*)d_in[5];
    const float* bv    = (const float*)d_in[6];
    const float* gamma = (const float*)d_in[7];

    float* out    = (float*)d_out;                   // [B,C,H,W]
    float* at_map = out + (size_t)BSZ * CIN * NPIX;  // [B,N,N] fp32

    const size_t qk_elems  = (size_t)BSZ * CQK * NPIX;   // 524288
    const size_t v_elems   = (size_t)BSZ * CIN * NPIX;   // 4194304
    const size_t nn_elems  = (size_t)BSZ * NPIX * NPIX;  // 67108864

    // fast path needs: q,k fp32 + v bf16 + attn bf16
    const size_t need_fast = 2 * qk_elems * 4 + v_elems * 2 + nn_elems * 2;

    if (ws_size >= need_fast) {
        float*          q       = (float*)d_ws;
        float*          k       = q + qk_elems;
        unsigned short* v_bf    = (unsigned short*)(k + qk_elems);
        unsigned short* attn_bf = v_bf + v_elems;

        proj_kernel<<<dim3(NPIX/1024, CQK/8, BSZ), 256, 0, stream>>>(x, wq, bq, q, CQK);
        proj_kernel<<<dim3(NPIX/1024, CQK/8, BSZ), 256, 0, stream>>>(x, wk, bk, k, CQK);
        proj_bf16_kernel<<<dim3(NPIX/1024, CIN/8, BSZ), 256, 0, stream>>>(x, wv, bv, v_bf, CIN);

        energy_softmax_kernel<<<dim3(NPIX/8, BSZ), 512, 0, stream>>>(q, k, at_map, attn_bf);

        sa_gemm_mfma<<<dim3(NPIX/128, CIN/128, BSZ), 256, 0, stream>>>(
            v_bf, attn_bf, x, gamma, out);
    } else {
        // fallback: all-fp32 path (round-1 kernels)
        float* q = (float*)d_ws;
        float* k = q + qk_elems;
        float* v = k + qk_elems;

        proj_kernel<<<dim3(NPIX/1024, CQK/8, BSZ), 256, 0, stream>>>(x, wq, bq, q, CQK);
        proj_kernel<<<dim3(NPIX/1024, CQK/8, BSZ), 256, 0, stream>>>(x, wk, bk, k, CQK);
        proj_kernel<<<dim3(NPIX/1024, CIN/8, BSZ), 256, 0, stream>>>(x, wv, bv, v, CIN);

        energy_softmax_kernel<<<dim3(NPIX/8, BSZ), 512, 0, stream>>>(q, k, at_map, nullptr);

        sa_gemm_kernel<<<dim3(NPIX/64, CIN/64, BSZ), 256, 0, stream>>>(
            v, at_map, x, gamma, out);
    }
}